// Round 4
// baseline (4088.089 us; speedup 1.0000x reference)
//
#include <hip/hip_runtime.h>

// ParallelAttention router: q,k,v = x@Wq|Wk|Wv (16384x2048 @ 2048x64),
// out[t][i] = sum_j softmax_j(q_i*k_j) * v_j, fp32 in/out.
//
// v4: deterministic v2 skeleton, occupancy via grid size.
//   1024 blocks x 256 thr; block = 16 tokens; wave = 16 rows x 48 cols
//   (3 16x16 tiles; 3 MFMAs each for hi*hi + lo*hi + hi*lo).
//   A: global->reg, 2-deep prefetch. B: L2-hot fragments, 1-deep double buffer.
//   No barriers in K-loop; single __syncthreads before softmax epilogue.

typedef __bf16 bf16x8 __attribute__((ext_vector_type(8)));
typedef float f32x4  __attribute__((ext_vector_type(4)));

#define NTOK   16384
#define HDIM   2048
#define NCHUNK 64                 // K chunks of 32
#define CH_STRIDE (12 * 2 * 512)  // bf16 elems per chunk in bfrag (12288)

// bfrag layout: [chunk 0..63][tile 0..11][hi=0/lo=1][lane 0..63][j 0..7]
// element = W_cat[k = chunk*32 + (lane>>4)*8 + j][n = tile*16 + (lane&15)]
// where W_cat cols: 0-63 = Wq, 64-127 = Wk, 128-191 = Wv.
__global__ void pack_w_kernel(const float* __restrict__ Wq,
                              const float* __restrict__ Wk,
                              const float* __restrict__ Wv,
                              __bf16* __restrict__ bfrag)
{
  int u = blockIdx.x * blockDim.x + threadIdx.x;   // (chunk, tile, lane)
  if (u >= NCHUNK * 12 * 64) return;
  int l  = u & 63;
  int tn = (u >> 6) % 12;
  int c  = u / (12 * 64);
  int n  = tn * 16 + (l & 15);
  int kb = c * 32 + ((l >> 4) << 3);
  const float* W = (n < 64) ? Wq : (n < 128) ? Wk : Wv;
  int nn = n & 63;
  bf16x8 hi, lo;
#pragma unroll
  for (int j = 0; j < 8; ++j) {
    float f = W[(size_t)(kb + j) * 64 + nn];
    __bf16 h = (__bf16)f;              // RNE
    hi[j] = h;
    lo[j] = (__bf16)(f - (float)h);    // residual
  }
  size_t base = (size_t)(c * 12 + tn) * 1024 + (size_t)l * 8;
  *(bf16x8*)(bfrag + base)       = hi;
  *(bf16x8*)(bfrag + base + 512) = lo;
}

__global__ __launch_bounds__(256, 4) void router_kernel(
    const float* __restrict__ x,
    const __bf16* __restrict__ bfrag,
    float* __restrict__ out)
{
  const int tok0 = blockIdx.x * 16;
  const int w    = threadIdx.x >> 6;   // col group: cols [48w, 48w+48)
  const int lane = threadIdx.x & 63;
  const int mr   = lane & 15;
  const int quad = lane >> 4;

  __shared__ float qkv[16 * 196];      // 16 tokens x 192 (+4 pad), fp32

  // A fragment: row = mr (token tok0+mr), k = chunk*32 + quad*8 + j
  const float*  a0 = x + (size_t)(tok0 + mr) * HDIM + quad * 8;
  const __bf16* bp = bfrag + (size_t)(3 * w) * 1024 + (size_t)lane * 8;

  f32x4 acc[3];
#pragma unroll
  for (int t = 0; t < 3; ++t)
    acc[t] = (f32x4){0.f, 0.f, 0.f, 0.f};

  // A: 2-deep register prefetch (HBM/L3 latency); B: 1-deep double buffer (L2-hot)
  float4 pA[2][2];
#pragma unroll
  for (int d = 0; d < 2; ++d) {
    pA[d][0] = *(const float4*)(a0 + d * 32);
    pA[d][1] = *(const float4*)(a0 + d * 32 + 4);
  }
  bf16x8 pBh[2][3], pBl[2][3];
#pragma unroll
  for (int t = 0; t < 3; ++t) {
    pBh[0][t] = *(const bf16x8*)(bp + (size_t)t * 1024);
    pBl[0][t] = *(const bf16x8*)(bp + (size_t)t * 1024 + 512);
  }

  for (int c = 0; c < NCHUNK; ++c) {
    const int b = c & 1;

    // prefetch B(c+1) into the other buffer
    if (c + 1 < NCHUNK) {
      const __bf16* nb = bp + (size_t)(c + 1) * CH_STRIDE;
#pragma unroll
      for (int t = 0; t < 3; ++t) {
        pBh[1 - b][t] = *(const bf16x8*)(nb + (size_t)t * 1024);
        pBl[1 - b][t] = *(const bf16x8*)(nb + (size_t)t * 1024 + 512);
      }
    }

    // consume A(c), then prefetch A(c+2) into the same slot
    float4 A0 = pA[b][0], A1 = pA[b][1];
    if (c + 2 < NCHUNK) {
      const float* na = a0 + (c + 2) * 32;
      pA[b][0] = *(const float4*)(na);
      pA[b][1] = *(const float4*)(na + 4);
    }

    // fp32 -> bf16 hi/lo split
    float av[8] = {A0.x, A0.y, A0.z, A0.w, A1.x, A1.y, A1.z, A1.w};
    bf16x8 ah, al;
#pragma unroll
    for (int j = 0; j < 8; ++j) {
      __bf16 h = (__bf16)av[j];
      ah[j] = h;
      al[j] = (__bf16)(av[j] - (float)h);
    }

#pragma unroll
    for (int t = 0; t < 3; ++t) {
      acc[t] = __builtin_amdgcn_mfma_f32_16x16x32_bf16(ah, pBh[b][t], acc[t], 0, 0, 0);
      acc[t] = __builtin_amdgcn_mfma_f32_16x16x32_bf16(al, pBh[b][t], acc[t], 0, 0, 0);
      acc[t] = __builtin_amdgcn_mfma_f32_16x16x32_bf16(ah, pBl[b][t], acc[t], 0, 0, 0);
    }
  }

  // C/D layout (m89-verified): col = lane&15, row = (lane>>4)*4 + reg
#pragma unroll
  for (int t = 0; t < 3; ++t) {
    int col = w * 48 + t * 16 + mr;
    int row = quad * 4;
#pragma unroll
    for (int r = 0; r < 4; ++r)
      qkv[(row + r) * 196 + col] = acc[t][r];
  }
  __syncthreads();

  // softmax epilogue: 16 threads per token, 4 outputs each.
  // No max-subtraction needed: |q_i*k_j| <~ 30, exp2(30*1.443) inside fp32.
  const int tt = threadIdx.x >> 4;     // token 0..15
  const int g  = threadIdx.x & 15;     // output group
  const float* qrow = qkv + tt * 196;
  float qs[4], lsum[4], osum[4];
#pragma unroll
  for (int ii = 0; ii < 4; ++ii) {
    qs[ii]   = qrow[g * 4 + ii] * 1.44269504f;   // log2(e)
    lsum[ii] = 0.f;
    osum[ii] = 0.f;
  }
  for (int j = 0; j < 64; ++j) {
    float kj = qrow[64 + j];
    float vj = qrow[128 + j];
#pragma unroll
    for (int ii = 0; ii < 4; ++ii) {
      float e = __builtin_amdgcn_exp2f(qs[ii] * kj);   // v_exp_f32
      lsum[ii] += e;
      osum[ii] = fmaf(e, vj, osum[ii]);
    }
  }
  float4 r;
  r.x = osum[0] / lsum[0];
  r.y = osum[1] / lsum[1];
  r.z = osum[2] / lsum[2];
  r.w = osum[3] / lsum[3];
  *(float4*)(out + (size_t)(tok0 + tt) * 64 + g * 4) = r;
}

extern "C" void kernel_launch(void* const* d_in, const int* in_sizes, int n_in,
                              void* d_out, int out_size, void* d_ws, size_t ws_size,
                              hipStream_t stream)
{
  const float* x  = (const float*)d_in[0];
  const float* Wq = (const float*)d_in[1];
  const float* Wk = (const float*)d_in[2];
  const float* Wv = (const float*)d_in[3];
  __bf16* bfrag   = (__bf16*)d_ws;          // needs 1.5 MiB of scratch
  float*  out     = (float*)d_out;

  pack_w_kernel<<<(NCHUNK * 12 * 64 + 255) / 256, 256, 0, stream>>>(Wq, Wk, Wv, bfrag);
  router_kernel<<<NTOK / 16, 256, 0, stream>>>(x, bfrag, out);
}

// Round 5
// 365.881 us; speedup vs baseline: 11.1733x; 11.1733x over previous
//
#include <hip/hip_runtime.h>

// ParallelAttention router: q,k,v = x@Wq|Wk|Wv (16384x2048 @ 2048x64),
// out[t][i] = sum_j softmax_j(q_i*k_j) * v_j, fp32 in/out.
//
// v5: v4 intent (16 tokens/block, 1024 blocks, 4 blocks/CU) but with a
// manually 2x-unrolled K-loop so ALL prefetch buffers use compile-time
// constant indices -> stay in VGPRs (R4's runtime-indexed buffers spilled
// to scratch: 1.2 GB of writes, 4 ms). No barriers in K-loop.

typedef __bf16 bf16x8 __attribute__((ext_vector_type(8)));
typedef float f32x4  __attribute__((ext_vector_type(4)));

#define NTOK   16384
#define HDIM   2048
#define NCHUNK 64                 // K chunks of 32
#define CH_STRIDE (12 * 2 * 512)  // bf16 elems per chunk in bfrag (12288)

// bfrag layout: [chunk 0..63][tile 0..11][hi=0/lo=1][lane 0..63][j 0..7]
// element = W_cat[k = chunk*32 + (lane>>4)*8 + j][n = tile*16 + (lane&15)]
// where W_cat cols: 0-63 = Wq, 64-127 = Wk, 128-191 = Wv.
__global__ void pack_w_kernel(const float* __restrict__ Wq,
                              const float* __restrict__ Wk,
                              const float* __restrict__ Wv,
                              __bf16* __restrict__ bfrag)
{
  int u = blockIdx.x * blockDim.x + threadIdx.x;   // (chunk, tile, lane)
  if (u >= NCHUNK * 12 * 64) return;
  int l  = u & 63;
  int tn = (u >> 6) % 12;
  int c  = u / (12 * 64);
  int n  = tn * 16 + (l & 15);
  int kb = c * 32 + ((l >> 4) << 3);
  const float* W = (n < 64) ? Wq : (n < 128) ? Wk : Wv;
  int nn = n & 63;
  bf16x8 hi, lo;
#pragma unroll
  for (int j = 0; j < 8; ++j) {
    float f = W[(size_t)(kb + j) * 64 + nn];
    __bf16 h = (__bf16)f;              // RNE
    hi[j] = h;
    lo[j] = (__bf16)(f - (float)h);    // residual
  }
  size_t base = (size_t)(c * 12 + tn) * 1024 + (size_t)l * 8;
  *(bf16x8*)(bfrag + base)       = hi;
  *(bf16x8*)(bfrag + base + 512) = lo;
}

__device__ __forceinline__ void split_a(const float4& Aa, const float4& Ab,
                                        bf16x8& ah, bf16x8& al)
{
  float av[8] = {Aa.x, Aa.y, Aa.z, Aa.w, Ab.x, Ab.y, Ab.z, Ab.w};
#pragma unroll
  for (int j = 0; j < 8; ++j) {
    __bf16 h = (__bf16)av[j];
    ah[j] = h;
    al[j] = (__bf16)(av[j] - (float)h);
  }
}

__global__ __launch_bounds__(256, 4) void router_kernel(
    const float* __restrict__ x,
    const __bf16* __restrict__ bfrag,
    float* __restrict__ out)
{
  const int tok0 = blockIdx.x * 16;
  const int w    = threadIdx.x >> 6;   // col group: cols [48w, 48w+48)
  const int lane = threadIdx.x & 63;
  const int mr   = lane & 15;
  const int quad = lane >> 4;

  __shared__ float qkv[16 * 196];      // 16 tokens x 192 (+4 pad), fp32

  // A fragment: row = mr (token tok0+mr), k = chunk*32 + quad*8 + j
  const float*  a0 = x + (size_t)(tok0 + mr) * HDIM + quad * 8;
  const __bf16* bp = bfrag + (size_t)(3 * w) * 1024 + (size_t)lane * 8;

  f32x4 acc[3];
#pragma unroll
  for (int t = 0; t < 3; ++t)
    acc[t] = (f32x4){0.f, 0.f, 0.f, 0.f};

  // Preload: A chunks 0,1 ; B chunk 0. All buffer names explicit.
  float4 A0a = *(const float4*)(a0);
  float4 A0b = *(const float4*)(a0 + 4);
  float4 A1a = *(const float4*)(a0 + 32);
  float4 A1b = *(const float4*)(a0 + 36);
  bf16x8 B0h[3], B0l[3], B1h[3], B1l[3];
#pragma unroll
  for (int t = 0; t < 3; ++t) {
    B0h[t] = *(const bf16x8*)(bp + (size_t)t * 1024);
    B0l[t] = *(const bf16x8*)(bp + (size_t)t * 1024 + 512);
  }

  for (int c = 0; c < NCHUNK; c += 2) {
    // prefetch B(c+1) -> B1  (c+1 <= 63 always)
    {
      const __bf16* nb = bp + (size_t)(c + 1) * CH_STRIDE;
#pragma unroll
      for (int t = 0; t < 3; ++t) {
        B1h[t] = *(const bf16x8*)(nb + (size_t)t * 1024);
        B1l[t] = *(const bf16x8*)(nb + (size_t)t * 1024 + 512);
      }
    }
    // prefetch A(c+2)
    float4 nA0a = A0a, nA0b = A0b;
    if (c + 2 < NCHUNK) {
      const float* na = a0 + (c + 2) * 32;
      nA0a = *(const float4*)(na);
      nA0b = *(const float4*)(na + 4);
    }

    // ---- compute chunk c with B0 ----
    {
      bf16x8 ah, al;
      split_a(A0a, A0b, ah, al);
#pragma unroll
      for (int t = 0; t < 3; ++t) {
        acc[t] = __builtin_amdgcn_mfma_f32_16x16x32_bf16(ah, B0h[t], acc[t], 0, 0, 0);
        acc[t] = __builtin_amdgcn_mfma_f32_16x16x32_bf16(al, B0h[t], acc[t], 0, 0, 0);
        acc[t] = __builtin_amdgcn_mfma_f32_16x16x32_bf16(ah, B0l[t], acc[t], 0, 0, 0);
      }
    }

    // prefetch B(c+2) -> B0 ; A(c+3)
    if (c + 2 < NCHUNK) {
      const __bf16* nb = bp + (size_t)(c + 2) * CH_STRIDE;
#pragma unroll
      for (int t = 0; t < 3; ++t) {
        B0h[t] = *(const bf16x8*)(nb + (size_t)t * 1024);
        B0l[t] = *(const bf16x8*)(nb + (size_t)t * 1024 + 512);
      }
    }
    float4 nA1a = A1a, nA1b = A1b;
    if (c + 3 < NCHUNK) {
      const float* na = a0 + (c + 3) * 32;
      nA1a = *(const float4*)(na);
      nA1b = *(const float4*)(na + 4);
    }

    // ---- compute chunk c+1 with B1 ----
    {
      bf16x8 ah, al;
      split_a(A1a, A1b, ah, al);
#pragma unroll
      for (int t = 0; t < 3; ++t) {
        acc[t] = __builtin_amdgcn_mfma_f32_16x16x32_bf16(ah, B1h[t], acc[t], 0, 0, 0);
        acc[t] = __builtin_amdgcn_mfma_f32_16x16x32_bf16(al, B1h[t], acc[t], 0, 0, 0);
        acc[t] = __builtin_amdgcn_mfma_f32_16x16x32_bf16(ah, B1l[t], acc[t], 0, 0, 0);
      }
    }

    A0a = nA0a; A0b = nA0b;
    A1a = nA1a; A1b = nA1b;
  }

  // C/D layout (m89-verified): col = lane&15, row = (lane>>4)*4 + reg
#pragma unroll
  for (int t = 0; t < 3; ++t) {
    int col = w * 48 + t * 16 + mr;
    int row = quad * 4;
#pragma unroll
    for (int r = 0; r < 4; ++r)
      qkv[(row + r) * 196 + col] = acc[t][r];
  }
  __syncthreads();

  // softmax epilogue: 16 threads per token, 4 outputs each.
  // No max-subtraction needed: |q_i*k_j| <~ 30, exp2(30*1.443) inside fp32.
  const int tt = threadIdx.x >> 4;     // token 0..15
  const int g  = threadIdx.x & 15;     // output group
  const float* qrow = qkv + tt * 196;
  float qs[4], lsum[4], osum[4];
#pragma unroll
  for (int ii = 0; ii < 4; ++ii) {
    qs[ii]   = qrow[g * 4 + ii] * 1.44269504f;   // log2(e)
    lsum[ii] = 0.f;
    osum[ii] = 0.f;
  }
  for (int j = 0; j < 64; ++j) {
    float kj = qrow[64 + j];
    float vj = qrow[128 + j];
#pragma unroll
    for (int ii = 0; ii < 4; ++ii) {
      float e = __builtin_amdgcn_exp2f(qs[ii] * kj);   // v_exp_f32
      lsum[ii] += e;
      osum[ii] = fmaf(e, vj, osum[ii]);
    }
  }
  float4 r;
  r.x = osum[0] / lsum[0];
  r.y = osum[1] / lsum[1];
  r.z = osum[2] / lsum[2];
  r.w = osum[3] / lsum[3];
  *(float4*)(out + (size_t)(tok0 + tt) * 64 + g * 4) = r;
}

extern "C" void kernel_launch(void* const* d_in, const int* in_sizes, int n_in,
                              void* d_out, int out_size, void* d_ws, size_t ws_size,
                              hipStream_t stream)
{
  const float* x  = (const float*)d_in[0];
  const float* Wq = (const float*)d_in[1];
  const float* Wk = (const float*)d_in[2];
  const float* Wv = (const float*)d_in[3];
  __bf16* bfrag   = (__bf16*)d_ws;          // needs 1.5 MiB of scratch
  float*  out     = (float*)d_out;

  pack_w_kernel<<<(NCHUNK * 12 * 64 + 255) / 256, 256, 0, stream>>>(Wq, Wk, Wv, bfrag);
  router_kernel<<<NTOK / 16, 256, 0, stream>>>(x, bfrag, out);
}